// Round 1
// baseline (195.074 us; speedup 1.0000x reference)
//
#include <hip/hip_runtime.h>
#include <math.h>
#include <float.h>

// Problem constants (match reference)
constexpr int Bn  = 64;
constexpr int ICn = 2;
constexpr int OCn = 32;
constexpr int Kn  = 5;
constexpr int Ln  = 65536;
constexpr float FSc = 50000000.0f;
constexpr int JMAXn = 16;

// Conv tiling
constexpr int TPB  = 256;
constexpr int LPT  = 4;            // outputs (l) per thread
constexpr int TILE = TPB * LPT;    // 1024 l per block
constexpr int NT   = Ln / TILE;    // 64 tiles per sample

// ---------------------------------------------------------------------------
// Kernel 1: per-sample steerable weight generation.
// grid = B, block = 64 (tid < 32 active, one oc each). Negligible cost.
// All small arrays use compile-time indices only -> stay in registers.
// ---------------------------------------------------------------------------
__global__ __launch_bounds__(64) void wgen_kernel(const int* __restrict__ z,
                                                  const float* __restrict__ s,
                                                  const float* __restrict__ w0,
                                                  float* __restrict__ w) {
    const int b  = blockIdx.x;
    const int oc = threadIdx.x;
    if (oc >= OCn) return;

    // --- params: where(z>0, nan_to_num(s), neutral) ---
    float pv[5];
#pragma unroll
    for (int c = 0; c < 5; ++c) {
        float v = s[b * 5 + c];
        if (isnan(v)) v = 0.0f;
        else if (isinf(v)) v = (v > 0.0f) ? FLT_MAX : -FLT_MAX;
        pv[c] = v;
    }
    const float neutral[5] = {0.0f, 1.0f, 1.0f, 0.0f, 0.0f};
#pragma unroll
    for (int c = 0; c < 5; ++c) {
        if (!(z[b * 5 + c] > 0)) pv[c] = neutral[c];
    }
    const float f0    = pv[0];
    const float alpha = pv[1];
    const float rho   = pv[2];
    const float a     = pv[4];

    // new_W = clip(round(K / max(alpha, 0.001)), 1, J_MAX)   (round half-to-even)
    float nw = rintf(5.0f / fmaxf(alpha, 0.001f));
    int new_W = (int)nw;
    if (new_W < 1) new_W = 1;
    if (new_W > JMAXn) new_W = JMAXn;
    const float nWf = (float)new_W;

    // --- M = W2 @ W1  (5x5), fully in registers ---
    float M[Kn][Kn];
#pragma unroll
    for (int xi = 0; xi < Kn; ++xi)
#pragma unroll
        for (int y = 0; y < Kn; ++y) M[xi][y] = 0.0f;

#pragma unroll
    for (int xi = 0; xi < Kn; ++xi) {
        const float src2 = fmaxf((xi + 0.5f) * nWf / 5.0f - 0.5f, 0.0f);
        const int   j0   = (int)floorf(src2);
        const int   j1   = min(j0 + 1, new_W - 1);
        const float lam2 = src2 - (float)j0;
        const int   jj[2] = {j0, j1};
        const float cf[2] = {1.0f - lam2, lam2};
#pragma unroll
        for (int t = 0; t < 2; ++t) {
            const int   j  = jj[t];
            const float cc = cf[t];
            // W1 row j (j < new_W always -> valid = 1)
            const float src1 = fmaxf((j + 0.5f) * 5.0f / nWf - 0.5f, 0.0f);
            const int   i0   = (int)floorf(src1);
            const int   i1   = min(i0 + 1, Kn - 1);
            const float lam1 = src1 - (float)i0;
#pragma unroll
            for (int y = 0; y < Kn; ++y) {
                const float e = ((y == i0) ? (1.0f - lam1) : 0.0f) +
                                ((y == i1) ? lam1 : 0.0f);
                M[xi][y] += cc * e;
            }
        }
    }

    // --- resample w0 taps: w[x] = sum_y M[x][y] * w0[oc, ic, y] ---
    const float* w0b = w0 + oc * (ICn * Kn);
    float wI[Kn], wQ[Kn];
#pragma unroll
    for (int xi = 0; xi < Kn; ++xi) {
        float aI = 0.0f, aQ = 0.0f;
#pragma unroll
        for (int y = 0; y < Kn; ++y) {
            aI += M[xi][y] * w0b[y];
            aQ += M[xi][y] * w0b[Kn + y];
        }
        wI[xi] = aI;
        wQ[xi] = aQ;
    }

    // --- rotations (f0 phase, then chirp), theta=0 skipped (exact identity), *rho ---
    const float c2pi = (float)(2.0 * M_PI);
    const float cpi  = (float)M_PI;
#pragma unroll
    for (int n = 0; n < Kn; ++n) {
        const float nf  = (float)n;
        const float ph1 = ((c2pi * f0) * nf) / FSc;
        const float c1 = cosf(ph1), s1 = sinf(ph1);
        float I = wI[n], Q = wQ[n];
        float I2 = I * c1 - Q * s1;
        float Q2 = I * s1 + Q * c1;
        const float t   = nf / FSc;
        const float ph2 = (cpi * a) * (t * t);
        const float c2 = cosf(ph2), s2 = sinf(ph2);
        float I3 = I2 * c2 - Q2 * s2;
        float Q3 = I2 * s2 + Q2 * c2;
        wI[n] = rho * I3;
        wQ[n] = rho * Q3;
    }

    float* wb = w + (b * OCn + oc) * (ICn * Kn);
#pragma unroll
    for (int k = 0; k < Kn; ++k) {
        wb[k]      = wI[k];
        wb[Kn + k] = wQ[k];
    }
}

// ---------------------------------------------------------------------------
// Kernel 2: grouped conv1d, "same" padding (pad=2), no kernel flip
// (XLA conv = cross-correlation).  Each thread: 4 consecutive l, all 32 oc.
// x window held in registers across the oc loop; weights are wave-uniform
// (scalar loads).  Stores: one float4 per oc -> perfectly coalesced.
// ---------------------------------------------------------------------------
__global__ __launch_bounds__(TPB) void conv_kernel(const float* __restrict__ x,
                                                   const float* __restrict__ w,
                                                   float* __restrict__ y) {
    const int blk  = blockIdx.x;
    const int b    = blk >> 6;          // NT = 64
    const int lt   = blk & (NT - 1);
    const int base = lt * TILE + (int)threadIdx.x * LPT;

    const float* xb = x + (size_t)b * (ICn * Ln);

    // x window [base-4, base+12): 12 floats per ic; used range is [base-2, base+6)
    float xr[ICn][12];
    if (base >= 4 && base + 8 <= Ln) {
#pragma unroll
        for (int ic = 0; ic < ICn; ++ic) {
            const float4 v0 = *reinterpret_cast<const float4*>(xb + ic * Ln + base - 4);
            const float4 v1 = *reinterpret_cast<const float4*>(xb + ic * Ln + base);
            const float4 v2 = *reinterpret_cast<const float4*>(xb + ic * Ln + base + 4);
            xr[ic][0] = v0.x; xr[ic][1] = v0.y; xr[ic][2]  = v0.z; xr[ic][3]  = v0.w;
            xr[ic][4] = v1.x; xr[ic][5] = v1.y; xr[ic][6]  = v1.z; xr[ic][7]  = v1.w;
            xr[ic][8] = v2.x; xr[ic][9] = v2.y; xr[ic][10] = v2.z; xr[ic][11] = v2.w;
        }
    } else {
#pragma unroll
        for (int ic = 0; ic < ICn; ++ic) {
#pragma unroll
            for (int m = 0; m < 12; ++m) {
                const int g = base - 4 + m;
                xr[ic][m] = (g >= 0 && g < Ln) ? xb[ic * Ln + g] : 0.0f;
            }
        }
    }

    const float* wb = w + b * (OCn * ICn * Kn);
    float* yb = y + ((size_t)b * OCn) * Ln + base;

#pragma unroll 2
    for (int oc = 0; oc < OCn; ++oc) {
        const float* wo = wb + oc * (ICn * Kn);
        float acc0 = 0.0f, acc1 = 0.0f, acc2 = 0.0f, acc3 = 0.0f;
#pragma unroll
        for (int ic = 0; ic < ICn; ++ic) {
#pragma unroll
            for (int k = 0; k < Kn; ++k) {
                const float wv = wo[ic * Kn + k];
                // output l = base + j needs x[base + j + k - 2] -> xr[j + k + 2]
                acc0 = fmaf(wv, xr[ic][k + 2], acc0);
                acc1 = fmaf(wv, xr[ic][k + 3], acc1);
                acc2 = fmaf(wv, xr[ic][k + 4], acc2);
                acc3 = fmaf(wv, xr[ic][k + 5], acc3);
            }
        }
        *reinterpret_cast<float4*>(yb + (size_t)oc * Ln) =
            make_float4(acc0, acc1, acc2, acc3);
    }
}

extern "C" void kernel_launch(void* const* d_in, const int* in_sizes, int n_in,
                              void* d_out, int out_size, void* d_ws, size_t ws_size,
                              hipStream_t stream) {
    const float* x  = (const float*)d_in[0];   // (B, IC, 1, L) f32
    const int*   z  = (const int*)d_in[1];     // (B, 5) i32
    const float* s  = (const float*)d_in[2];   // (B, 5) f32
    const float* w0 = (const float*)d_in[3];   // (OC, IC, 1, K) f32
    float* y = (float*)d_out;                  // (B, OC, 1, L) f32
    float* w = (float*)d_ws;                   // B*OC*IC*K = 20480 floats (80 KB)

    hipLaunchKernelGGL(wgen_kernel, dim3(Bn), dim3(64), 0, stream, z, s, w0, w);
    hipLaunchKernelGGL(conv_kernel, dim3(Bn * NT), dim3(TPB), 0, stream, x, w, y);
}